// Round 1
// baseline (203.735 us; speedup 1.0000x reference)
//
#include <hip/hip_runtime.h>

// ProbsNet: out = mean over 5 of [p_m @ tmp_{0 or 1}]
//   tmp_t[i] = sum_d sigmoid(pB*(pBEV*BEV + ST_t[i,d])) * W_t[i,d]
//
// R6: counters showed latency/burstiness bound (VALUBusy 9%, HBM 17% peak,
// nothing saturated). Old structure = one-shot 8-load burst + vmcnt(0) +
// compute + block exit: all waves' memory phases aligned -> memory idles
// during compute/turnover (21 block generations/CU, 21 pipeline drains).
// New structure: each block owns 4 consecutive chunks of ONE row; two
// register buffers rotate with ISSUE(next) / s_waitcnt vmcnt(8) /
// compute(prev) so 8-16 loads stay outstanding continuously. vmcnt(0)
// only at the last chunk. Turnover drops to ~5 generations/CU.

#define D_DIM          131072
#define N_ROWS         84
#define ROW_F4         (D_DIM / 4)                      // 32768 f4 per row
#define F4_PER_CHUNK   1024                             // f4 per block-chunk
#define CHUNK_BYTES    (F4_PER_CHUNK * 16)              // 16384
#define CPB            4                                // chunks per block (divides 32)
#define BLOCKS_PER_ROW (ROW_F4 / (F4_PER_CHUNK * CPB))  // 8
#define T0_BLOCKS      (N_ROWS * BLOCKS_PER_ROW)        // 672
#define BLOCKS         (2 * T0_BLOCKS)                  // 1344

typedef float f32x4 __attribute__((ext_vector_type(4)));

// entry t of calc_probs(logits): i=t/21; r=t%21
//   r==0 -> p_i ; else r-=1, j=r/5, s=r%5: s==0 -> p_i*p_j else p_i*p_j*p_{s-1}
__device__ inline float prob_entry(const float* __restrict__ logits, int t) {
    float l0 = logits[0], l1 = logits[1], l2 = logits[2], l3 = logits[3];
    float m  = fmaxf(fmaxf(l0, l1), fmaxf(l2, l3));
    float e0 = __expf(l0 - m), e1 = __expf(l1 - m);
    float e2 = __expf(l2 - m), e3 = __expf(l3 - m);
    float inv = 1.0f / (e0 + e1 + e2 + e3);
    float p[4] = {e0 * inv, e1 * inv, e2 * inv, e3 * inv};
    int i = t / 21;
    int r = t - i * 21;
    if (r == 0) return p[i];
    r -= 1;
    int j = r / 5;
    int s = r - j * 5;
    float v = p[i] * p[j];
    return (s == 0) ? v : v * p[s - 1];
}

// w * sigmoid(pb*(bev+s)) = w * rcp(1 + exp2(a*s + ab)), a = -pb*log2(e)
__device__ inline float sigdot(float w, float s, float a, float ab) {
    float e = __builtin_amdgcn_exp2f(fmaf(a, s, ab));
    return w * __builtin_amdgcn_rcpf(1.0f + e);
}

// 8 x 16B loads via SGPR base + 32-bit voffset. Volatile asm blocks keep
// mutual program order; consumers are ordered by register dataflow.
#define ISSUE8(S0, S1, S2, S3, Wa, Wb_, Wc, Wd, off, SB, WB)               \
    asm volatile(                                                          \
        "global_load_dwordx4 %0, %8, %12\n\t"                              \
        "global_load_dwordx4 %4, %8, %13\n\t"                              \
        "global_load_dwordx4 %1, %9, %12\n\t"                              \
        "global_load_dwordx4 %5, %9, %13\n\t"                              \
        "global_load_dwordx4 %2, %10, %12\n\t"                             \
        "global_load_dwordx4 %6, %10, %13\n\t"                             \
        "global_load_dwordx4 %3, %11, %12\n\t"                             \
        "global_load_dwordx4 %7, %11, %13"                                 \
        : "=&v"(S0), "=&v"(S1), "=&v"(S2), "=&v"(S3),                      \
          "=&v"(Wa), "=&v"(Wb_), "=&v"(Wc), "=&v"(Wd)                      \
        : "v"(off), "v"((off) + 4096u), "v"((off) + 8192u),                \
          "v"((off) + 12288u), "s"(SB), "s"(WB))

// Wait until only the 8 newest loads remain outstanding -> the 8 loads of
// the buffer named here are complete. "+v" makes every later use of the
// buffer depend on this asm, so nothing can be hoisted above the wait.
#define WAIT_PREV8(S0, S1, S2, S3, Wa, Wb_, Wc, Wd)                        \
    asm volatile("s_waitcnt vmcnt(8)"                                      \
                 : "+v"(S0), "+v"(S1), "+v"(S2), "+v"(S3),                 \
                   "+v"(Wa), "+v"(Wb_), "+v"(Wc), "+v"(Wd))

#define WAIT_ALL8(S0, S1, S2, S3, Wa, Wb_, Wc, Wd)                         \
    asm volatile("s_waitcnt vmcnt(0)"                                      \
                 : "+v"(S0), "+v"(S1), "+v"(S2), "+v"(S3),                 \
                   "+v"(Wa), "+v"(Wb_), "+v"(Wc), "+v"(Wd))

#define ACC16(S0, S1, S2, S3, Wa, Wb_, Wc, Wd)                             \
    do {                                                                   \
        acc += sigdot(Wa[0], S0[0], a, ab);                                \
        acc += sigdot(Wa[1], S0[1], a, ab);                                \
        acc += sigdot(Wa[2], S0[2], a, ab);                                \
        acc += sigdot(Wa[3], S0[3], a, ab);                                \
        acc += sigdot(Wb_[0], S1[0], a, ab);                               \
        acc += sigdot(Wb_[1], S1[1], a, ab);                               \
        acc += sigdot(Wb_[2], S1[2], a, ab);                               \
        acc += sigdot(Wb_[3], S1[3], a, ab);                               \
        acc += sigdot(Wc[0], S2[0], a, ab);                                \
        acc += sigdot(Wc[1], S2[1], a, ab);                                \
        acc += sigdot(Wc[2], S2[2], a, ab);                                \
        acc += sigdot(Wc[3], S2[3], a, ab);                                \
        acc += sigdot(Wd[0], S3[0], a, ab);                                \
        acc += sigdot(Wd[1], S3[1], a, ab);                                \
        acc += sigdot(Wd[2], S3[2], a, ab);                                \
        acc += sigdot(Wd[3], S3[3], a, ab);                                \
    } while (0)

__global__ __launch_bounds__(256, 4) void probsnet_main(
    const float* __restrict__ BEV,
    const float* __restrict__ ST0, const float* __restrict__ W0,
    const float* __restrict__ ST1, const float* __restrict__ W1,
    const float* __restrict__ probs0, const float* __restrict__ probs1,
    const float* __restrict__ probs2, const float* __restrict__ probs3,
    const float* __restrict__ probs4,
    const float* __restrict__ pBEV, const float* __restrict__ pB,
    float* __restrict__ partials)
{
    const int bid    = blockIdx.x;
    const int t      = threadIdx.x;
    const int tensor = (bid >= T0_BLOCKS) ? 1 : 0;
    const int cb     = bid - tensor * T0_BLOCKS;   // block index within tensor
    const int row    = cb / BLOCKS_PER_ROW;        // one row per block (CPB | 32)

    const float pb  = pB[0];
    const float bev = pBEV[0] * BEV[0];
    const float a   = -pb * 1.4426950408889634f;   // -pb*log2(e)
    const float ab  = a * bev;

    const float* Sb = tensor ? ST1 : ST0;
    const float* Wb = tensor ? W1  : W0;

    // byte offset of this thread's first float4 within the tensor
    const unsigned base = (unsigned)(cb * (CPB * F4_PER_CHUNK) + t) * 16u;

    f32x4 as0, as1, as2, as3, aw0, aw1, aw2, aw3;   // buffer A
    f32x4 bs0, bs1, bs2, bs3, bw0, bw1, bw2, bw3;   // buffer B

    float acc = 0.0f;

    // chunk0 -> A, chunk1 -> B, then rotate: wait(prev 8), compute, issue next.
    ISSUE8(as0, as1, as2, as3, aw0, aw1, aw2, aw3, base,                   Sb, Wb);
    ISSUE8(bs0, bs1, bs2, bs3, bw0, bw1, bw2, bw3, base + 1u * CHUNK_BYTES, Sb, Wb);

    WAIT_PREV8(as0, as1, as2, as3, aw0, aw1, aw2, aw3);      // chunk0 ready
    ACC16(as0, as1, as2, as3, aw0, aw1, aw2, aw3);
    ISSUE8(as0, as1, as2, as3, aw0, aw1, aw2, aw3, base + 2u * CHUNK_BYTES, Sb, Wb);

    WAIT_PREV8(bs0, bs1, bs2, bs3, bw0, bw1, bw2, bw3);      // chunk1 ready
    ACC16(bs0, bs1, bs2, bs3, bw0, bw1, bw2, bw3);
    ISSUE8(bs0, bs1, bs2, bs3, bw0, bw1, bw2, bw3, base + 3u * CHUNK_BYTES, Sb, Wb);

    WAIT_PREV8(as0, as1, as2, as3, aw0, aw1, aw2, aw3);      // chunk2 ready
    ACC16(as0, as1, as2, as3, aw0, aw1, aw2, aw3);

    WAIT_ALL8(bs0, bs1, bs2, bs3, bw0, bw1, bw2, bw3);       // chunk3 ready
    ACC16(bs0, bs1, bs2, bs3, bw0, bw1, bw2, bw3);

    // wave64 shuffle reduction
    #pragma unroll
    for (int off = 32; off > 0; off >>= 1)
        acc += __shfl_down(acc, off, 64);

    __shared__ float red[4];
    const int wave = t >> 6;
    const int lane = t & 63;
    if (lane == 0) red[wave] = acc;
    __syncthreads();

    if (t == 0) {
        const float S = red[0] + red[1] + red[2] + red[3];
        float pw;
        if (tensor == 0) {
            pw = prob_entry(probs0, row);
        } else {
            pw = prob_entry(probs1, row) + prob_entry(probs2, row)
               + prob_entry(probs3, row) + prob_entry(probs4, row);
        }
        partials[bid] = pw * S;
    }
}

__global__ __launch_bounds__(256) void probsnet_reduce(
    const float* __restrict__ partials, float* __restrict__ out)
{
    const int t = threadIdx.x;
    float acc = 0.0f;
    for (int k = t; k < BLOCKS; k += 256)   // 1344 partials
        acc += partials[k];

    #pragma unroll
    for (int off = 32; off > 0; off >>= 1)
        acc += __shfl_down(acc, off, 64);

    __shared__ float red[4];
    const int wave = t >> 6;
    const int lane = t & 63;
    if (lane == 0) red[wave] = acc;
    __syncthreads();

    if (t == 0)
        out[0] = (red[0] + red[1] + red[2] + red[3]) * 0.2f;
}

extern "C" void kernel_launch(void* const* d_in, const int* in_sizes, int n_in,
                              void* d_out, int out_size, void* d_ws, size_t ws_size,
                              hipStream_t stream) {
    // setup_inputs order:
    // 0=BEV(1) 1=ST0 2=Weight0 3=ST1 4=Weight1 5=Problem(int,unused)
    // 6..10=probs0..probs4(4) 11=pBEV(1) 12=pB(1)
    const float* BEV    = (const float*)d_in[0];
    const float* ST0    = (const float*)d_in[1];
    const float* W0     = (const float*)d_in[2];
    const float* ST1    = (const float*)d_in[3];
    const float* W1     = (const float*)d_in[4];
    const float* probs0 = (const float*)d_in[6];
    const float* probs1 = (const float*)d_in[7];
    const float* probs2 = (const float*)d_in[8];
    const float* probs3 = (const float*)d_in[9];
    const float* probs4 = (const float*)d_in[10];
    const float* pBEV   = (const float*)d_in[11];
    const float* pB     = (const float*)d_in[12];

    float* partials = (float*)d_ws;          // 1344 floats of scratch
    float* out      = (float*)d_out;

    probsnet_main<<<BLOCKS, 256, 0, stream>>>(
        BEV, ST0, W0, ST1, W1,
        probs0, probs1, probs2, probs3, probs4,
        pBEV, pB, partials);

    probsnet_reduce<<<1, 256, 0, stream>>>(partials, out);
}